// Round 3
// baseline (851.073 us; speedup 1.0000x reference)
//
#include <hip/hip_runtime.h>
#include <stdint.h>

#define NUM_KP 17
#define BATCH  32
#define HDIM   256
#define WDIM   256
#define NCH    (BATCH * NUM_KP)     // 544 channels
#define MAXP   30
#define CAP_G  8192                 // per-channel candidate cap (expected ~7400)
#define BANDROWS 32
#define NBANDS (HDIM / BANDROWS)    // 8 bands/channel -> 4352 blocks

// 13-bit score quantization: q = (float_bits >> 12) - QBASE, clamped [1, 8191].
// Scores > 0.1f (bits > 0x3DCCCCCD) give q >= 1; score 1.0 -> q = 6965.
// 11 mantissa bits -> ~16 candidates/bin at the top for uniform-noise maxima.
#define QBASE  253131
#define NBINS3 8192

// ws layout: [0, NCH*4) int counters; candidates (u32) at +4096, CAP_G per channel.
#define CAND_OFF 4096
#define WS_REQUIRED ((size_t)CAND_OFF + (size_t)NCH * CAP_G * 4)

__device__ __forceinline__ unsigned long long shfl_down_u64(unsigned long long v, int off) {
    unsigned lo = (unsigned)v, hi = (unsigned)(v >> 32);
    lo = __shfl_down(lo, off);
    hi = __shfl_down(hi, off);
    return ((unsigned long long)hi << 32) | lo;
}
__device__ __forceinline__ unsigned long long shfl_u64(unsigned long long v, int lane) {
    unsigned lo = (unsigned)v, hi = (unsigned)(v >> 32);
    lo = __shfl(lo, lane);
    hi = __shfl(hi, lane);
    return ((unsigned long long)hi << 32) | lo;
}

__device__ __forceinline__ unsigned quant13(float v) {
    unsigned q = (__float_as_uint(v) >> 12);
    int b = (int)q - QBASE;
    b = b < 1 ? 1 : (b > NBINS3 - 1 ? NBINS3 - 1 : b);
    return (unsigned)b;
}

// ---------------- Kernel 1: barrier-free NMS + candidate append ----------------
__global__ __launch_bounds__(256)
void nms_kernel(const float* __restrict__ heat, int* __restrict__ cnt,
                unsigned* __restrict__ cand) {
    const float NEGINF = -__builtin_inff();
    const int chan = blockIdx.x >> 3;          // / NBANDS
    const int band = blockIdx.x & (NBANDS - 1);
    const int wave = threadIdx.x >> 6;
    const int lane = threadIdx.x & 63;
    const float* __restrict__ cp = heat + (size_t)chan * (HDIM * WDIM);
    unsigned* __restrict__ ccand = cand + (size_t)chan * CAP_G;
    int* ccnt = cnt + chan;

    const int rows_per_wave = BANDROWS / 4;    // 8
    const int r0 = band * BANDROWS + wave * rows_per_wave;

    for (int rr = 0; rr < rows_per_wave; ++rr) {
        const int r = r0 + rr;
        const float* rp = cp + (r << 8) + (lane << 2);
        float4 up, md, dn;
        md = *(const float4*)rp;
        if (r > 0)        up = *(const float4*)(rp - WDIM);
        else              up = make_float4(NEGINF, NEGINF, NEGINF, NEGINF);
        if (r < HDIM - 1) dn = *(const float4*)(rp + WDIM);
        else              dn = make_float4(NEGINF, NEGINF, NEGINF, NEGINF);

        float vm0 = fmaxf(up.x, fmaxf(md.x, dn.x));
        float vm1 = fmaxf(up.y, fmaxf(md.y, dn.y));
        float vm2 = fmaxf(up.z, fmaxf(md.z, dn.z));
        float vm3 = fmaxf(up.w, fmaxf(md.w, dn.w));
        float left  = __shfl_up(vm3, 1);   if (lane == 0)  left  = NEGINF;
        float right = __shfl_down(vm0, 1); if (lane == 63) right = NEGINF;
        float h0 = fmaxf(left, fmaxf(vm0, vm1));
        float h1 = fmaxf(vm0, fmaxf(vm1, vm2));
        float h2 = fmaxf(vm1, fmaxf(vm2, vm3));
        float h3 = fmaxf(vm2, fmaxf(vm3, right));

        const int base = (r << 8) | (lane << 2);
        if (md.x > 0.1f && md.x == h0) {
            int pos = atomicAdd(ccnt, 1);
            if (pos < CAP_G) ccand[pos] = (quant13(md.x) << 16) | (unsigned)(base + 0);
        }
        if (md.y > 0.1f && md.y == h1) {
            int pos = atomicAdd(ccnt, 1);
            if (pos < CAP_G) ccand[pos] = (quant13(md.y) << 16) | (unsigned)(base + 1);
        }
        if (md.z > 0.1f && md.z == h2) {
            int pos = atomicAdd(ccnt, 1);
            if (pos < CAP_G) ccand[pos] = (quant13(md.z) << 16) | (unsigned)(base + 2);
        }
        if (md.w > 0.1f && md.w == h3) {
            int pos = atomicAdd(ccnt, 1);
            if (pos < CAP_G) ccand[pos] = (quant13(md.w) << 16) | (unsigned)(base + 3);
        }
    }
}

// ---------------- Kernel 2: per-channel exact top-30 ----------------
__global__ __launch_bounds__(256)
void topk_kernel(const float* __restrict__ heat, const int* __restrict__ cnt,
                 const unsigned* __restrict__ cand, float* __restrict__ out, int out_size) {
    __shared__ int s_hist[NBINS3];              // 32 KB
    __shared__ int s_gsum[256];                 // 1 KB (each = sum of 32 bins)
    __shared__ unsigned long long s_ref[256];   // 2 KB
    __shared__ int s_nref, s_tau;

    const int tid  = threadIdx.x;
    const int chan = blockIdx.x;
    const float NEGINF = -__builtin_inff();
    const float* chanptr = heat + (size_t)chan * (HDIM * WDIM);
    const unsigned* cc = cand + (size_t)chan * CAP_G;
    int n = cnt[chan]; if (n > CAP_G) n = CAP_G;

    for (int i = tid; i < NBINS3; i += 256) s_hist[i] = 0;
    if (tid == 0) s_nref = 0;
    __syncthreads();

    // histogram on 13-bit quantized score
    for (int i = tid; i < n; i += 256) {
        unsigned p = cc[i];
        atomicAdd(&s_hist[p >> 16], 1);
    }
    __syncthreads();

    {   // two-level suffix scan: 256 groups of 32 bins
        int s = 0;
        #pragma unroll
        for (int j = 0; j < 32; ++j) s += s_hist[tid * 32 + j];
        s_gsum[tid] = s;
    }
    __syncthreads();
    if (tid == 0) {
        int cum = 0, tau = 0;
        for (int g = 255; g >= 0; --g) {
            int gs = s_gsum[g];
            if (cum + gs >= MAXP) {
                for (int b = g * 32 + 31; b >= g * 32; --b) {
                    cum += s_hist[b];
                    if (cum >= MAXP) { tau = b; break; }
                }
                break;
            }
            cum += gs;
        }
        s_tau = tau;   // stays 0 if total < MAXP -> collect all
    }
    __syncthreads();

    // collect survivors (q >= tau), re-read exact scores (expected ~46)
    const unsigned tau = (unsigned)s_tau;
    for (int i = tid; i < n; i += 256) {
        unsigned p = cc[i];
        if ((p >> 16) >= tau) {
            int pos = atomicAdd(&s_nref, 1);
            if (pos < 256) {
                unsigned idx = p & 0xFFFFu;
                float sc = chanptr[idx];
                // key: higher score wins; tie -> smaller idx (matches lax.top_k)
                s_ref[pos] = ((unsigned long long)__float_as_uint(sc) << 32) | (unsigned)(~idx);
            }
        }
    }
    __syncthreads();
    const int nref = s_nref < 256 ? s_nref : 256;

    // exact top-30 extraction, wave 0 only
    if (tid < 64) {
        unsigned long long k0 = (tid       < nref) ? s_ref[tid]       : 0ull;
        unsigned long long k1 = (tid + 64  < nref) ? s_ref[tid + 64]  : 0ull;
        unsigned long long k2 = (tid + 128 < nref) ? s_ref[tid + 128] : 0ull;
        unsigned long long k3 = (tid + 192 < nref) ? s_ref[tid + 192] : 0ull;
        for (int r = 0; r < MAXP; ++r) {
            unsigned long long best = k0; int bs = 0;
            if (k1 > best) { best = k1; bs = 1; }
            if (k2 > best) { best = k2; bs = 2; }
            if (k3 > best) { best = k3; bs = 3; }
            unsigned long long key = best;
            int slot = (bs << 6) | tid;
            #pragma unroll
            for (int off = 32; off > 0; off >>= 1) {
                unsigned long long ok = shfl_down_u64(key, off);
                int os = __shfl_down(slot, off);
                if (ok > key) { key = ok; slot = os; }
            }
            key  = shfl_u64(key, 0);
            slot = __shfl(slot, 0);
            if ((slot & 63) == tid) {
                int which = slot >> 6;
                if      (which == 0) k0 = 0ull;
                else if (which == 1) k1 = 0ull;
                else if (which == 2) k2 = 0ull;
                else                 k3 = 0ull;
            }
            if (tid == 0) {
                float sc, vld; unsigned idx;
                if (key != 0ull) {
                    sc  = __uint_as_float((unsigned)(key >> 32));
                    idx = (~(unsigned)key) & 0xFFFFu;
                    vld = 1.0f;
                } else { sc = NEGINF; idx = 0u; vld = 0.0f; }
                int x = (int)(idx & 255), y = (int)(idx >> 8);
                long long cb = ((long long)chan * MAXP + r) * 2;
                if (cb + 1 < out_size) {
                    out[cb]     = (float)(x * 4);
                    out[cb + 1] = (float)(y * 4);
                }
                long long so = (long long)NCH * MAXP * 2 + (long long)chan * MAXP + r;
                if (so < out_size) out[so] = sc;
                long long vo = (long long)NCH * MAXP * 3 + (long long)chan * MAXP + r;
                if (vo < out_size) out[vo] = vld;
            }
        }
    }
}

// ---------------- Fallback: R1 single-kernel (used only if ws too small) ----------------
#define CAP    8192
#define NBINS  2048
#define BIN_BASE 128001
#define TILE   16
#define SLOTS  (TILE + 2)
#define RSTRIDE 264

__global__ __launch_bounds__(256, 2)
void pose_post_kernel(const float* __restrict__ heat, float* __restrict__ out, int out_size) {
    __shared__ __align__(16) float rowsL[SLOTS * RSTRIDE];
    __shared__ unsigned s_cand[CAP];
    __shared__ int s_hist[NBINS];
    __shared__ int s_gsum[NBINS / 8];
    __shared__ unsigned long long s_ref[256];
    __shared__ int s_cnt, s_nref, s_tau;

    const int tid  = threadIdx.x;
    const int chan = blockIdx.x;
    const float* chanptr = heat + (size_t)chan * (HDIM * WDIM);
    const float NEGINF = -__builtin_inff();

    for (int i = tid; i < NBINS; i += 256) s_hist[i] = 0;
    if (tid < SLOTS) {
        rowsL[tid * RSTRIDE + 3]        = NEGINF;
        rowsL[tid * RSTRIDE + 4 + WDIM] = NEGINF;
    }
    if (tid == 0) { s_cnt = 0; s_nref = 0; }
    __syncthreads();

    for (int tile = 0; tile < HDIM / TILE; ++tile) {
        const int y0 = tile * TILE;
        for (int i = tid; i < SLOTS * (WDIM / 4); i += 256) {
            int row = i >> 6;
            int c   = (i & 63) << 2;
            int gy  = y0 - 1 + row;
            float4 v;
            if (gy >= 0 && gy < HDIM) v = *(const float4*)(chanptr + (gy << 8) + c);
            else                      v = make_float4(NEGINF, NEGINF, NEGINF, NEGINF);
            *(float4*)(&rowsL[row * RSTRIDE + 4 + c]) = v;
        }
        __syncthreads();

        const int t = tid;
        float a0 = rowsL[0 * RSTRIDE + 3 + t];
        float b0 = rowsL[0 * RSTRIDE + 4 + t];
        float c0 = rowsL[0 * RSTRIDE + 5 + t];
        float h0 = fmaxf(a0, fmaxf(b0, c0));
        float a1 = rowsL[1 * RSTRIDE + 3 + t];
        float b1 = rowsL[1 * RSTRIDE + 4 + t];
        float c1 = rowsL[1 * RSTRIDE + 5 + t];
        float h1 = fmaxf(a1, fmaxf(b1, c1));
        float m1 = b1;
        #pragma unroll 4
        for (int r = 1; r <= TILE; ++r) {
            float a = rowsL[(r + 1) * RSTRIDE + 3 + t];
            float b = rowsL[(r + 1) * RSTRIDE + 4 + t];
            float c = rowsL[(r + 1) * RSTRIDE + 5 + t];
            float h2 = fmaxf(a, fmaxf(b, c));
            float v  = m1;
            float hm = fmaxf(h0, fmaxf(h1, h2));
            if (v == hm && v > 0.1f) {
                int idx = ((y0 + r - 1) << 8) | t;
                unsigned bits = __float_as_uint(v);
                int bin = (int)(bits >> 13) - BIN_BASE;
                bin = bin < 0 ? 0 : (bin > NBINS - 1 ? NBINS - 1 : bin);
                int pos = atomicAdd(&s_cnt, 1);
                if (pos < CAP) s_cand[pos] = ((unsigned)bin << 16) | (unsigned)idx;
                atomicAdd(&s_hist[bin], 1);
            }
            h0 = h1; h1 = h2; m1 = b;
        }
        __syncthreads();
    }

    {
        int s = 0;
        #pragma unroll
        for (int j = 0; j < 8; ++j) s += s_hist[tid * 8 + j];
        s_gsum[tid] = s;
    }
    __syncthreads();
    if (tid == 0) {
        int cum = 0, tau = 0;
        for (int g = NBINS / 8 - 1; g >= 0; --g) {
            int gs = s_gsum[g];
            if (cum + gs >= MAXP) {
                for (int b = g * 8 + 7; b >= g * 8; --b) {
                    cum += s_hist[b];
                    if (cum >= MAXP) { tau = b; break; }
                }
                break;
            }
            cum += gs;
        }
        s_tau = tau;
    }
    __syncthreads();

    const int tau   = s_tau;
    const int count = s_cnt < CAP ? s_cnt : CAP;
    for (int i = tid; i < count; i += 256) {
        unsigned p = s_cand[i];
        if ((int)(p >> 16) >= tau) {
            int pos = atomicAdd(&s_nref, 1);
            if (pos < 256) {
                unsigned idx = p & 0xFFFFu;
                float sc = chanptr[idx];
                s_ref[pos] = ((unsigned long long)__float_as_uint(sc) << 32) | (unsigned)(~idx);
            }
        }
    }
    __syncthreads();
    const int nref = s_nref < 256 ? s_nref : 256;

    if (tid < 64) {
        unsigned long long k0 = (tid       < nref) ? s_ref[tid]       : 0ull;
        unsigned long long k1 = (tid + 64  < nref) ? s_ref[tid + 64]  : 0ull;
        unsigned long long k2 = (tid + 128 < nref) ? s_ref[tid + 128] : 0ull;
        unsigned long long k3 = (tid + 192 < nref) ? s_ref[tid + 192] : 0ull;
        for (int r = 0; r < MAXP; ++r) {
            unsigned long long best = k0; int bs = 0;
            if (k1 > best) { best = k1; bs = 1; }
            if (k2 > best) { best = k2; bs = 2; }
            if (k3 > best) { best = k3; bs = 3; }
            unsigned long long key = best;
            int slot = (bs << 6) | tid;
            #pragma unroll
            for (int off = 32; off > 0; off >>= 1) {
                unsigned long long ok = shfl_down_u64(key, off);
                int os = __shfl_down(slot, off);
                if (ok > key) { key = ok; slot = os; }
            }
            key  = shfl_u64(key, 0);
            slot = __shfl(slot, 0);
            if ((slot & 63) == tid) {
                int which = slot >> 6;
                if      (which == 0) k0 = 0ull;
                else if (which == 1) k1 = 0ull;
                else if (which == 2) k2 = 0ull;
                else                 k3 = 0ull;
            }
            if (tid == 0) {
                float sc, vld; unsigned idx;
                if (key != 0ull) {
                    sc  = __uint_as_float((unsigned)(key >> 32));
                    idx = (~(unsigned)key) & 0xFFFFu;
                    vld = 1.0f;
                } else { sc = NEGINF; idx = 0u; vld = 0.0f; }
                int x = (int)(idx & 255), y = (int)(idx >> 8);
                long long cb = ((long long)chan * MAXP + r) * 2;
                if (cb + 1 < out_size) {
                    out[cb]     = (float)(x * 4);
                    out[cb + 1] = (float)(y * 4);
                }
                long long so = (long long)NCH * MAXP * 2 + (long long)chan * MAXP + r;
                if (so < out_size) out[so] = sc;
                long long vo = (long long)NCH * MAXP * 3 + (long long)chan * MAXP + r;
                if (vo < out_size) out[vo] = vld;
            }
        }
    }
}

extern "C" void kernel_launch(void* const* d_in, const int* in_sizes, int n_in,
                              void* d_out, int out_size, void* d_ws, size_t ws_size,
                              hipStream_t stream) {
    const float* heat = (const float*)d_in[0];
    float* out = (float*)d_out;
    if (ws_size >= WS_REQUIRED) {
        int* cnt = (int*)d_ws;
        unsigned* cand = (unsigned*)((char*)d_ws + CAND_OFF);
        hipMemsetAsync(d_ws, 0, NCH * sizeof(int), stream);
        hipLaunchKernelGGL(nms_kernel, dim3(NCH * NBANDS), dim3(256), 0, stream, heat, cnt, cand);
        hipLaunchKernelGGL(topk_kernel, dim3(NCH), dim3(256), 0, stream, heat, cnt, cand, out, out_size);
    } else {
        hipLaunchKernelGGL(pose_post_kernel, dim3(NCH), dim3(256), 0, stream, heat, out, out_size);
    }
}

// Round 4
// 246.278 us; speedup vs baseline: 3.4557x; 3.4557x over previous
//
#include <hip/hip_runtime.h>
#include <stdint.h>

#define NUM_KP 17
#define BATCH  32
#define HDIM   256
#define WDIM   256
#define NCH    (BATCH * NUM_KP)     // 544 channels
#define MAXP   30
#define CAP_G  8192                 // per-channel candidate cap (expected ~7340, +10 sigma)
#define NBANDS 8                    // 8 bands of 32 rows -> 4352 blocks
#define BUFCAP 1536                 // per-block LDS candidate buffer (expected ~915, +22 sigma)

// 13-bit score quantization: q = (float_bits >> 12) - QBASE, clamped [1, 8191].
// Scores > 0.1f give q >= 1; 11 mantissa bits -> ~16 cands/bin at the top.
#define QBASE  253131
#define NBINS3 8192

// ws layout: [0, NCH*4) int counters; candidates (u32) at +4096, CAP_G per channel.
#define CAND_OFF 4096
#define WS_REQUIRED ((size_t)CAND_OFF + (size_t)NCH * CAP_G * 4)

__device__ __forceinline__ unsigned long long shfl_down_u64(unsigned long long v, int off) {
    unsigned lo = (unsigned)v, hi = (unsigned)(v >> 32);
    lo = __shfl_down(lo, off);
    hi = __shfl_down(hi, off);
    return ((unsigned long long)hi << 32) | lo;
}
__device__ __forceinline__ unsigned long long shfl_u64(unsigned long long v, int lane) {
    unsigned lo = (unsigned)v, hi = (unsigned)(v >> 32);
    lo = __shfl(lo, lane);
    hi = __shfl(hi, lane);
    return ((unsigned long long)hi << 32) | lo;
}

__device__ __forceinline__ unsigned quant13(float v) {
    unsigned q = (__float_as_uint(v) >> 12);
    int b = (int)q - QBASE;
    b = b < 1 ? 1 : (b > NBINS3 - 1 ? NBINS3 - 1 : b);
    return (unsigned)b;
}

// ---------------- Kernel 1: NMS; LDS-buffered append, ONE global atomic per block --------
__global__ __launch_bounds__(256)
void nms_kernel(const float* __restrict__ heat, int* __restrict__ cnt,
                unsigned* __restrict__ cand) {
    __shared__ unsigned s_buf[BUFCAP];
    __shared__ int s_cnt, s_base;
    const float NEGINF = -__builtin_inff();
    const int chan = blockIdx.x >> 3;          // / NBANDS
    const int band = blockIdx.x & (NBANDS - 1);
    const int wave = threadIdx.x >> 6;
    const int lane = threadIdx.x & 63;
    const float* __restrict__ cp = heat + (size_t)chan * (HDIM * WDIM);

    if (threadIdx.x == 0) s_cnt = 0;
    __syncthreads();

    const int r0 = band * 32 + wave * 8;       // this wave owns rows r0..r0+7
    const float* colp = cp + (lane << 2);
    const float4 NEG4 = make_float4(NEGINF, NEGINF, NEGINF, NEGINF);

    float4 rm = (r0 > 0) ? *(const float4*)(colp + ((r0 - 1) << 8)) : NEG4;
    float4 rc = *(const float4*)(colp + (r0 << 8));

    for (int rr = 0; rr < 8; ++rr) {
        const int r = r0 + rr;
        float4 rp = (r + 1 < HDIM) ? *(const float4*)(colp + ((r + 1) << 8)) : NEG4;

        float vm0 = fmaxf(rm.x, fmaxf(rc.x, rp.x));
        float vm1 = fmaxf(rm.y, fmaxf(rc.y, rp.y));
        float vm2 = fmaxf(rm.z, fmaxf(rc.z, rp.z));
        float vm3 = fmaxf(rm.w, fmaxf(rc.w, rp.w));
        float left  = __shfl_up(vm3, 1);   if (lane == 0)  left  = NEGINF;
        float right = __shfl_down(vm0, 1); if (lane == 63) right = NEGINF;
        float h0 = fmaxf(left, fmaxf(vm0, vm1));
        float h1 = fmaxf(vm0, fmaxf(vm1, vm2));
        float h2 = fmaxf(vm1, fmaxf(vm2, vm3));
        float h3 = fmaxf(vm2, fmaxf(vm3, right));

        const int base = (r << 8) | (lane << 2);
        if (rc.x > 0.1f && rc.x == h0) {
            int pos = atomicAdd(&s_cnt, 1);
            if (pos < BUFCAP) s_buf[pos] = (quant13(rc.x) << 16) | (unsigned)(base + 0);
        }
        if (rc.y > 0.1f && rc.y == h1) {
            int pos = atomicAdd(&s_cnt, 1);
            if (pos < BUFCAP) s_buf[pos] = (quant13(rc.y) << 16) | (unsigned)(base + 1);
        }
        if (rc.z > 0.1f && rc.z == h2) {
            int pos = atomicAdd(&s_cnt, 1);
            if (pos < BUFCAP) s_buf[pos] = (quant13(rc.z) << 16) | (unsigned)(base + 2);
        }
        if (rc.w > 0.1f && rc.w == h3) {
            int pos = atomicAdd(&s_cnt, 1);
            if (pos < BUFCAP) s_buf[pos] = (quant13(rc.w) << 16) | (unsigned)(base + 3);
        }
        rm = rc; rc = rp;
    }
    __syncthreads();

    if (threadIdx.x == 0) {
        int m = s_cnt < BUFCAP ? s_cnt : BUFCAP;
        s_cnt  = m;
        s_base = atomicAdd(&cnt[chan], m);     // ONE global atomic per block
    }
    __syncthreads();

    const int m = s_cnt, gbase = s_base;
    unsigned* __restrict__ ccand = cand + (size_t)chan * CAP_G;
    for (int i = threadIdx.x; i < m; i += 256) {
        int gi = gbase + i;
        if (gi < CAP_G) ccand[gi] = s_buf[i];  // coalesced flush
    }
}

// ---------------- Kernel 2: per-channel exact top-30 (unchanged from R3) ----------------
__global__ __launch_bounds__(256)
void topk_kernel(const float* __restrict__ heat, const int* __restrict__ cnt,
                 const unsigned* __restrict__ cand, float* __restrict__ out, int out_size) {
    __shared__ int s_hist[NBINS3];              // 32 KB
    __shared__ int s_gsum[256];                 // 1 KB
    __shared__ unsigned long long s_ref[256];   // 2 KB
    __shared__ int s_nref, s_tau;

    const int tid  = threadIdx.x;
    const int chan = blockIdx.x;
    const float NEGINF = -__builtin_inff();
    const float* chanptr = heat + (size_t)chan * (HDIM * WDIM);
    const unsigned* cc = cand + (size_t)chan * CAP_G;
    int n = cnt[chan]; if (n > CAP_G) n = CAP_G;

    for (int i = tid; i < NBINS3; i += 256) s_hist[i] = 0;
    if (tid == 0) s_nref = 0;
    __syncthreads();

    for (int i = tid; i < n; i += 256) {
        unsigned p = cc[i];
        atomicAdd(&s_hist[p >> 16], 1);
    }
    __syncthreads();

    {
        int s = 0;
        #pragma unroll
        for (int j = 0; j < 32; ++j) s += s_hist[tid * 32 + j];
        s_gsum[tid] = s;
    }
    __syncthreads();
    if (tid == 0) {
        int cum = 0, tau = 0;
        for (int g = 255; g >= 0; --g) {
            int gs = s_gsum[g];
            if (cum + gs >= MAXP) {
                for (int b = g * 32 + 31; b >= g * 32; --b) {
                    cum += s_hist[b];
                    if (cum >= MAXP) { tau = b; break; }
                }
                break;
            }
            cum += gs;
        }
        s_tau = tau;   // stays 0 if total < MAXP -> collect all
    }
    __syncthreads();

    const unsigned tau = (unsigned)s_tau;
    for (int i = tid; i < n; i += 256) {
        unsigned p = cc[i];
        if ((p >> 16) >= tau) {
            int pos = atomicAdd(&s_nref, 1);
            if (pos < 256) {
                unsigned idx = p & 0xFFFFu;
                float sc = chanptr[idx];
                // key: higher score wins; tie -> smaller idx (matches lax.top_k)
                s_ref[pos] = ((unsigned long long)__float_as_uint(sc) << 32) | (unsigned)(~idx);
            }
        }
    }
    __syncthreads();
    const int nref = s_nref < 256 ? s_nref : 256;

    if (tid < 64) {
        unsigned long long k0 = (tid       < nref) ? s_ref[tid]       : 0ull;
        unsigned long long k1 = (tid + 64  < nref) ? s_ref[tid + 64]  : 0ull;
        unsigned long long k2 = (tid + 128 < nref) ? s_ref[tid + 128] : 0ull;
        unsigned long long k3 = (tid + 192 < nref) ? s_ref[tid + 192] : 0ull;
        for (int r = 0; r < MAXP; ++r) {
            unsigned long long best = k0; int bs = 0;
            if (k1 > best) { best = k1; bs = 1; }
            if (k2 > best) { best = k2; bs = 2; }
            if (k3 > best) { best = k3; bs = 3; }
            unsigned long long key = best;
            int slot = (bs << 6) | tid;
            #pragma unroll
            for (int off = 32; off > 0; off >>= 1) {
                unsigned long long ok = shfl_down_u64(key, off);
                int os = __shfl_down(slot, off);
                if (ok > key) { key = ok; slot = os; }
            }
            key  = shfl_u64(key, 0);
            slot = __shfl(slot, 0);
            if ((slot & 63) == tid) {
                int which = slot >> 6;
                if      (which == 0) k0 = 0ull;
                else if (which == 1) k1 = 0ull;
                else if (which == 2) k2 = 0ull;
                else                 k3 = 0ull;
            }
            if (tid == 0) {
                float sc, vld; unsigned idx;
                if (key != 0ull) {
                    sc  = __uint_as_float((unsigned)(key >> 32));
                    idx = (~(unsigned)key) & 0xFFFFu;
                    vld = 1.0f;
                } else { sc = NEGINF; idx = 0u; vld = 0.0f; }
                int x = (int)(idx & 255), y = (int)(idx >> 8);
                long long cb = ((long long)chan * MAXP + r) * 2;
                if (cb + 1 < out_size) {
                    out[cb]     = (float)(x * 4);
                    out[cb + 1] = (float)(y * 4);
                }
                long long so = (long long)NCH * MAXP * 2 + (long long)chan * MAXP + r;
                if (so < out_size) out[so] = sc;
                long long vo = (long long)NCH * MAXP * 3 + (long long)chan * MAXP + r;
                if (vo < out_size) out[vo] = vld;
            }
        }
    }
}

// ---------------- Fallback: R1 single-kernel (used only if ws too small) ----------------
#define CAP    8192
#define NBINS  2048
#define BIN_BASE 128001
#define TILE   16
#define SLOTS  (TILE + 2)
#define RSTRIDE 264

__global__ __launch_bounds__(256, 2)
void pose_post_kernel(const float* __restrict__ heat, float* __restrict__ out, int out_size) {
    __shared__ __align__(16) float rowsL[SLOTS * RSTRIDE];
    __shared__ unsigned s_cand[CAP];
    __shared__ int s_hist[NBINS];
    __shared__ int s_gsum[NBINS / 8];
    __shared__ unsigned long long s_ref[256];
    __shared__ int s_cnt, s_nref, s_tau;

    const int tid  = threadIdx.x;
    const int chan = blockIdx.x;
    const float* chanptr = heat + (size_t)chan * (HDIM * WDIM);
    const float NEGINF = -__builtin_inff();

    for (int i = tid; i < NBINS; i += 256) s_hist[i] = 0;
    if (tid < SLOTS) {
        rowsL[tid * RSTRIDE + 3]        = NEGINF;
        rowsL[tid * RSTRIDE + 4 + WDIM] = NEGINF;
    }
    if (tid == 0) { s_cnt = 0; s_nref = 0; }
    __syncthreads();

    for (int tile = 0; tile < HDIM / TILE; ++tile) {
        const int y0 = tile * TILE;
        for (int i = tid; i < SLOTS * (WDIM / 4); i += 256) {
            int row = i >> 6;
            int c   = (i & 63) << 2;
            int gy  = y0 - 1 + row;
            float4 v;
            if (gy >= 0 && gy < HDIM) v = *(const float4*)(chanptr + (gy << 8) + c);
            else                      v = make_float4(NEGINF, NEGINF, NEGINF, NEGINF);
            *(float4*)(&rowsL[row * RSTRIDE + 4 + c]) = v;
        }
        __syncthreads();

        const int t = tid;
        float a0 = rowsL[0 * RSTRIDE + 3 + t];
        float b0 = rowsL[0 * RSTRIDE + 4 + t];
        float c0 = rowsL[0 * RSTRIDE + 5 + t];
        float h0 = fmaxf(a0, fmaxf(b0, c0));
        float a1 = rowsL[1 * RSTRIDE + 3 + t];
        float b1 = rowsL[1 * RSTRIDE + 4 + t];
        float c1 = rowsL[1 * RSTRIDE + 5 + t];
        float h1 = fmaxf(a1, fmaxf(b1, c1));
        float m1 = b1;
        #pragma unroll 4
        for (int r = 1; r <= TILE; ++r) {
            float a = rowsL[(r + 1) * RSTRIDE + 3 + t];
            float b = rowsL[(r + 1) * RSTRIDE + 4 + t];
            float c = rowsL[(r + 1) * RSTRIDE + 5 + t];
            float h2 = fmaxf(a, fmaxf(b, c));
            float v  = m1;
            float hm = fmaxf(h0, fmaxf(h1, h2));
            if (v == hm && v > 0.1f) {
                int idx = ((y0 + r - 1) << 8) | t;
                unsigned bits = __float_as_uint(v);
                int bin = (int)(bits >> 13) - BIN_BASE;
                bin = bin < 0 ? 0 : (bin > NBINS - 1 ? NBINS - 1 : bin);
                int pos = atomicAdd(&s_cnt, 1);
                if (pos < CAP) s_cand[pos] = ((unsigned)bin << 16) | (unsigned)idx;
                atomicAdd(&s_hist[bin], 1);
            }
            h0 = h1; h1 = h2; m1 = b;
        }
        __syncthreads();
    }

    {
        int s = 0;
        #pragma unroll
        for (int j = 0; j < 8; ++j) s += s_hist[tid * 8 + j];
        s_gsum[tid] = s;
    }
    __syncthreads();
    if (tid == 0) {
        int cum = 0, tau = 0;
        for (int g = NBINS / 8 - 1; g >= 0; --g) {
            int gs = s_gsum[g];
            if (cum + gs >= MAXP) {
                for (int b = g * 8 + 7; b >= g * 8; --b) {
                    cum += s_hist[b];
                    if (cum >= MAXP) { tau = b; break; }
                }
                break;
            }
            cum += gs;
        }
        s_tau = tau;
    }
    __syncthreads();

    const int tau   = s_tau;
    const int count = s_cnt < CAP ? s_cnt : CAP;
    for (int i = tid; i < count; i += 256) {
        unsigned p = s_cand[i];
        if ((int)(p >> 16) >= tau) {
            int pos = atomicAdd(&s_nref, 1);
            if (pos < 256) {
                unsigned idx = p & 0xFFFFu;
                float sc = chanptr[idx];
                s_ref[pos] = ((unsigned long long)__float_as_uint(sc) << 32) | (unsigned)(~idx);
            }
        }
    }
    __syncthreads();
    const int nref = s_nref < 256 ? s_nref : 256;

    if (tid < 64) {
        unsigned long long k0 = (tid       < nref) ? s_ref[tid]       : 0ull;
        unsigned long long k1 = (tid + 64  < nref) ? s_ref[tid + 64]  : 0ull;
        unsigned long long k2 = (tid + 128 < nref) ? s_ref[tid + 128] : 0ull;
        unsigned long long k3 = (tid + 192 < nref) ? s_ref[tid + 192] : 0ull;
        for (int r = 0; r < MAXP; ++r) {
            unsigned long long best = k0; int bs = 0;
            if (k1 > best) { best = k1; bs = 1; }
            if (k2 > best) { best = k2; bs = 2; }
            if (k3 > best) { best = k3; bs = 3; }
            unsigned long long key = best;
            int slot = (bs << 6) | tid;
            #pragma unroll
            for (int off = 32; off > 0; off >>= 1) {
                unsigned long long ok = shfl_down_u64(key, off);
                int os = __shfl_down(slot, off);
                if (ok > key) { key = ok; slot = os; }
            }
            key  = shfl_u64(key, 0);
            slot = __shfl(slot, 0);
            if ((slot & 63) == tid) {
                int which = slot >> 6;
                if      (which == 0) k0 = 0ull;
                else if (which == 1) k1 = 0ull;
                else if (which == 2) k2 = 0ull;
                else                 k3 = 0ull;
            }
            if (tid == 0) {
                float sc, vld; unsigned idx;
                if (key != 0ull) {
                    sc  = __uint_as_float((unsigned)(key >> 32));
                    idx = (~(unsigned)key) & 0xFFFFu;
                    vld = 1.0f;
                } else { sc = NEGINF; idx = 0u; vld = 0.0f; }
                int x = (int)(idx & 255), y = (int)(idx >> 8);
                long long cb = ((long long)chan * MAXP + r) * 2;
                if (cb + 1 < out_size) {
                    out[cb]     = (float)(x * 4);
                    out[cb + 1] = (float)(y * 4);
                }
                long long so = (long long)NCH * MAXP * 2 + (long long)chan * MAXP + r;
                if (so < out_size) out[so] = sc;
                long long vo = (long long)NCH * MAXP * 3 + (long long)chan * MAXP + r;
                if (vo < out_size) out[vo] = vld;
            }
        }
    }
}

extern "C" void kernel_launch(void* const* d_in, const int* in_sizes, int n_in,
                              void* d_out, int out_size, void* d_ws, size_t ws_size,
                              hipStream_t stream) {
    const float* heat = (const float*)d_in[0];
    float* out = (float*)d_out;
    if (ws_size >= WS_REQUIRED) {
        int* cnt = (int*)d_ws;
        unsigned* cand = (unsigned*)((char*)d_ws + CAND_OFF);
        hipMemsetAsync(d_ws, 0, NCH * sizeof(int), stream);
        hipLaunchKernelGGL(nms_kernel, dim3(NCH * NBANDS), dim3(256), 0, stream, heat, cnt, cand);
        hipLaunchKernelGGL(topk_kernel, dim3(NCH), dim3(256), 0, stream, heat, cnt, cand, out, out_size);
    } else {
        hipLaunchKernelGGL(pose_post_kernel, dim3(NCH), dim3(256), 0, stream, heat, out, out_size);
    }
}